// Round 9
// baseline (36.045 us; speedup 1.0000x reference)
//
#include <hip/hip_runtime.h>
#include <hip/hip_bf16.h>
#include <math.h>

// NCM classifier: B=1024, C=500, F=512 (fp32 in/out).
//   xs = x / variance[0]
//   dist[b][c] = sqrt(sum_f (xs[b][f] - means[c][f])^2)
//   out = concat(softmax(-dist, axis=1), -dist, dist)   // each [B][C]
//
// dist^2 = ||xs||^2 + ||m||^2 - 2*(xs.m), cross term via bf16 MFMA (K=512).
// SINGLE compute kernel + tiny memset node:
//   memset: zero 32 per-band fan-in counters in d_ws
//   k1: per-block LDS staging (fp32->bf16 + exact fp32 norms) -> 16x16 MFMA
//       tiles -> write -dist/dist -> fan-in atomic; the 8th (last) block of
//       each 32-row band computes that band's softmax (reads expo, L3-hot).
//       Cross-XCD visibility: __syncthreads drains block stores to L2;
//       agent-scope ACQ_REL RMW does L2 writeback (release) / invalidate
//       (acquire) per the CDNA4 memory model (guide G16).
#define NB 1024
#define NC 500
#define NCP 512
#define NF 512
#define LSTR 520   // LDS row stride (bf16): 1040 B, 16B-aligned, bank-spread

typedef __attribute__((ext_vector_type(8))) short bf16x8;
typedef __attribute__((ext_vector_type(4))) float f32x4;

union bfpack { bf16x8 v; __hip_bfloat162 h[4]; };

// ---- k1: fused stage + GEMM + distance + fan-in softmax --------------------
__global__ __launch_bounds__(512) void ncm_dist_fused(
    const float* __restrict__ x, const float* __restrict__ means,
    const float* __restrict__ variance, float* __restrict__ out,
    uint* __restrict__ cnt)
{
    __shared__ ushort sA[32][LSTR];   // x rows (bf16, scaled)   65.0 KB
    __shared__ ushort sB[64][LSTR];   // means rows (bf16)       (A+B = 99.8 KB)
    __shared__ float  sNx[32];
    __shared__ float  sNm[64];
    __shared__ uint   s_old;

    const int t    = threadIdx.x;
    const int w    = t >> 6;          // wave 0..7
    const int lane = t & 63;
    const int fr   = lane & 15;
    const int g    = lane >> 4;
    const int b0   = blockIdx.x * 32;
    const int c0   = blockIdx.y * 64;
    const float inv_var = 1.0f / variance[0];

    // ---- stage: 96 rows (32 x + 64 means), 12 rows per wave ----
    #pragma unroll
    for (int j = 0; j < 12; ++j) {
        const int ri = w * 12 + j;            // 0..95
        const float* src;
        ushort* dst;
        float* nrm;
        float scale;
        bool zero = false;
        if (ri < 32) {
            src = x + (size_t)(b0 + ri) * NF;  dst = &sA[ri][0];
            nrm = &sNx[ri];                    scale = inv_var;
        } else {
            const int cm = c0 + ri - 32;
            src = means + (size_t)cm * NF;     dst = &sB[ri - 32][0];
            nrm = &sNm[ri - 32];               scale = 1.0f;
            zero = (cm >= NC);
        }

        float4 v0, v1;
        if (!zero) {
            v0 = *reinterpret_cast<const float4*>(&src[lane * 8]);
            v1 = *reinterpret_cast<const float4*>(&src[lane * 8 + 4]);
            v0.x *= scale; v0.y *= scale; v0.z *= scale; v0.w *= scale;
            v1.x *= scale; v1.y *= scale; v1.z *= scale; v1.w *= scale;
        } else {
            v0 = make_float4(0.f, 0.f, 0.f, 0.f);
            v1 = v0;
        }
        bfpack p;
        p.h[0] = __float22bfloat162_rn(make_float2(v0.x, v0.y));
        p.h[1] = __float22bfloat162_rn(make_float2(v0.z, v0.w));
        p.h[2] = __float22bfloat162_rn(make_float2(v1.x, v1.y));
        p.h[3] = __float22bfloat162_rn(make_float2(v1.z, v1.w));
        *reinterpret_cast<bf16x8*>(&dst[lane * 8]) = p.v;

        float s = v0.x * v0.x + v0.y * v0.y + v0.z * v0.z + v0.w * v0.w
                + v1.x * v1.x + v1.y * v1.y + v1.z * v1.z + v1.w * v1.w;
        #pragma unroll
        for (int off = 32; off > 0; off >>= 1) s += __shfl_xor(s, off, 64);
        if (lane == 0) *nrm = s;
    }
    __syncthreads();

    // ---- MFMA: wave w -> 16x16 tile at (b-half w>>2, c-quarter w&3) ----
    const int ar = (w >> 2) * 16 + fr;
    const int br = (w & 3) * 16 + fr;
    const ushort* ap = &sA[ar][g * 8];
    const ushort* bp = &sB[br][g * 8];

    f32x4 acc = {0.f, 0.f, 0.f, 0.f};
    #pragma unroll
    for (int ks = 0; ks < 16; ++ks) {
        bf16x8 a = *reinterpret_cast<const bf16x8*>(ap + ks * 32);
        bf16x8 b = *reinterpret_cast<const bf16x8*>(bp + ks * 32);
        acc = __builtin_amdgcn_mfma_f32_16x16x32_bf16(a, b, acc, 0, 0, 0);
    }

    // C/D layout (m89/m91): col = lane&15 -> class, row = g*4+r -> b-row
    const int c = c0 + (w & 3) * 16 + fr;
    float* expo  = out + (size_t)NB * NC;
    float* cdiff = out + (size_t)2 * NB * NC;
    if (c < NC) {
        const float nmc = sNm[(w & 3) * 16 + fr];
        #pragma unroll
        for (int r = 0; r < 4; ++r) {
            const int bl = (w >> 2) * 16 + g * 4 + r;
            const int b  = b0 + bl;
            float d2 = sNx[bl] + nmc - 2.0f * acc[r];
            float d = sqrtf(fmaxf(d2, 0.0f));
            expo[(size_t)b * NC + c]  = -d;
            cdiff[(size_t)b * NC + c] = d;
        }
    }

    // ---- fan-in: 8 blocks per 32-row band; last one does the softmax ----
    __syncthreads();   // all block stores drained to this XCD's L2
    if (t == 0) {
        s_old = __hip_atomic_fetch_add(&cnt[blockIdx.x], 1u,
                                       __ATOMIC_ACQ_REL,
                                       __HIP_MEMORY_SCOPE_AGENT);
    }
    __syncthreads();
    if (s_old != 7u) return;

    // winner: softmax for rows b0..b0+31 (wave w -> rows b0+4w..b0+4w+3)
    float* probs = out;
    #pragma unroll
    for (int i = 0; i < 4; ++i) {
        const int b = b0 + w * 4 + i;
        const float* erow = expo + (size_t)b * NC;
        float* prow = probs + (size_t)b * NC;

        const int base = lane * 8;
        const bool val0 = base + 3 < NC;
        const bool val1 = base + 7 < NC;
        const float4 ninf = make_float4(-1e30f, -1e30f, -1e30f, -1e30f);

        float4 v0 = val0 ? *reinterpret_cast<const float4*>(&erow[base])     : ninf;
        float4 v1 = val1 ? *reinterpret_cast<const float4*>(&erow[base + 4]) : ninf;

        float m = fmaxf(fmaxf(fmaxf(v0.x, v0.y), fmaxf(v0.z, v0.w)),
                        fmaxf(fmaxf(v1.x, v1.y), fmaxf(v1.z, v1.w)));
        #pragma unroll
        for (int off = 32; off > 0; off >>= 1)
            m = fmaxf(m, __shfl_xor(m, off, 64));

        float4 e0, e1;
        e0.x = expf(v0.x - m); e0.y = expf(v0.y - m);
        e0.z = expf(v0.z - m); e0.w = expf(v0.w - m);
        e1.x = expf(v1.x - m); e1.y = expf(v1.y - m);
        e1.z = expf(v1.z - m); e1.w = expf(v1.w - m);

        float s = e0.x + e0.y + e0.z + e0.w + e1.x + e1.y + e1.z + e1.w;
        #pragma unroll
        for (int off = 32; off > 0; off >>= 1)
            s += __shfl_xor(s, off, 64);
        const float inv = 1.0f / s;

        e0.x *= inv; e0.y *= inv; e0.z *= inv; e0.w *= inv;
        e1.x *= inv; e1.y *= inv; e1.z *= inv; e1.w *= inv;

        if (val0) *reinterpret_cast<float4*>(&prow[base])     = e0;
        if (val1) *reinterpret_cast<float4*>(&prow[base + 4]) = e1;
    }
}

// ---- fallback k2 (2-kernel path, proven R8) --------------------------------
__global__ __launch_bounds__(64) void ncm_softmax_kernel(float* __restrict__ out)
{
    const int b = blockIdx.x;
    const int lane = threadIdx.x;
    const float* expo = out + (size_t)NB * NC + (size_t)b * NC;
    float* probs = out + (size_t)b * NC;

    const int base = lane * 8;
    const bool val0 = base + 3 < NC;
    const bool val1 = base + 7 < NC;
    const float4 ninf = make_float4(-1e30f, -1e30f, -1e30f, -1e30f);

    float4 v0 = val0 ? *reinterpret_cast<const float4*>(&expo[base])     : ninf;
    float4 v1 = val1 ? *reinterpret_cast<const float4*>(&expo[base + 4]) : ninf;

    float m = fmaxf(fmaxf(fmaxf(v0.x, v0.y), fmaxf(v0.z, v0.w)),
                    fmaxf(fmaxf(v1.x, v1.y), fmaxf(v1.z, v1.w)));
    #pragma unroll
    for (int off = 32; off > 0; off >>= 1)
        m = fmaxf(m, __shfl_xor(m, off, 64));

    float4 e0, e1;
    e0.x = expf(v0.x - m); e0.y = expf(v0.y - m);
    e0.z = expf(v0.z - m); e0.w = expf(v0.w - m);
    e1.x = expf(v1.x - m); e1.y = expf(v1.y - m);
    e1.z = expf(v1.z - m); e1.w = expf(v1.w - m);

    float s = e0.x + e0.y + e0.z + e0.w + e1.x + e1.y + e1.z + e1.w;
    #pragma unroll
    for (int off = 32; off > 0; off >>= 1)
        s += __shfl_xor(s, off, 64);
    float inv = 1.0f / s;

    e0.x *= inv; e0.y *= inv; e0.z *= inv; e0.w *= inv;
    e1.x *= inv; e1.y *= inv; e1.z *= inv; e1.w *= inv;

    if (val0) *reinterpret_cast<float4*>(&probs[base])     = e0;
    if (val1) *reinterpret_cast<float4*>(&probs[base + 4]) = e1;
}

// fallback version of the fused kernel without the fan-in tail
__global__ __launch_bounds__(512) void ncm_dist_only(
    const float* __restrict__ x, const float* __restrict__ means,
    const float* __restrict__ variance, float* __restrict__ out)
{
    __shared__ ushort sA[32][LSTR];
    __shared__ ushort sB[64][LSTR];
    __shared__ float  sNx[32];
    __shared__ float  sNm[64];

    const int t    = threadIdx.x;
    const int w    = t >> 6;
    const int lane = t & 63;
    const int fr   = lane & 15;
    const int g    = lane >> 4;
    const int b0   = blockIdx.x * 32;
    const int c0   = blockIdx.y * 64;
    const float inv_var = 1.0f / variance[0];

    #pragma unroll
    for (int j = 0; j < 12; ++j) {
        const int ri = w * 12 + j;
        const float* src;
        ushort* dst;
        float* nrm;
        float scale;
        bool zero = false;
        if (ri < 32) {
            src = x + (size_t)(b0 + ri) * NF;  dst = &sA[ri][0];
            nrm = &sNx[ri];                    scale = inv_var;
        } else {
            const int cm = c0 + ri - 32;
            src = means + (size_t)cm * NF;     dst = &sB[ri - 32][0];
            nrm = &sNm[ri - 32];               scale = 1.0f;
            zero = (cm >= NC);
        }
        float4 v0, v1;
        if (!zero) {
            v0 = *reinterpret_cast<const float4*>(&src[lane * 8]);
            v1 = *reinterpret_cast<const float4*>(&src[lane * 8 + 4]);
            v0.x *= scale; v0.y *= scale; v0.z *= scale; v0.w *= scale;
            v1.x *= scale; v1.y *= scale; v1.z *= scale; v1.w *= scale;
        } else {
            v0 = make_float4(0.f, 0.f, 0.f, 0.f);
            v1 = v0;
        }
        bfpack p;
        p.h[0] = __float22bfloat162_rn(make_float2(v0.x, v0.y));
        p.h[1] = __float22bfloat162_rn(make_float2(v0.z, v0.w));
        p.h[2] = __float22bfloat162_rn(make_float2(v1.x, v1.y));
        p.h[3] = __float22bfloat162_rn(make_float2(v1.z, v1.w));
        *reinterpret_cast<bf16x8*>(&dst[lane * 8]) = p.v;

        float s = v0.x * v0.x + v0.y * v0.y + v0.z * v0.z + v0.w * v0.w
                + v1.x * v1.x + v1.y * v1.y + v1.z * v1.z + v1.w * v1.w;
        #pragma unroll
        for (int off = 32; off > 0; off >>= 1) s += __shfl_xor(s, off, 64);
        if (lane == 0) *nrm = s;
    }
    __syncthreads();

    const int ar = (w >> 2) * 16 + fr;
    const int br = (w & 3) * 16 + fr;
    const ushort* ap = &sA[ar][g * 8];
    const ushort* bp = &sB[br][g * 8];

    f32x4 acc = {0.f, 0.f, 0.f, 0.f};
    #pragma unroll
    for (int ks = 0; ks < 16; ++ks) {
        bf16x8 a = *reinterpret_cast<const bf16x8*>(ap + ks * 32);
        bf16x8 b = *reinterpret_cast<const bf16x8*>(bp + ks * 32);
        acc = __builtin_amdgcn_mfma_f32_16x16x32_bf16(a, b, acc, 0, 0, 0);
    }

    const int c = c0 + (w & 3) * 16 + fr;
    if (c < NC) {
        const float nmc = sNm[(w & 3) * 16 + fr];
        float* expo  = out + (size_t)NB * NC;
        float* cdiff = out + (size_t)2 * NB * NC;
        #pragma unroll
        for (int r = 0; r < 4; ++r) {
            const int bl = (w >> 2) * 16 + g * 4 + r;
            const int b  = b0 + bl;
            float d2 = sNx[bl] + nmc - 2.0f * acc[r];
            float d = sqrtf(fmaxf(d2, 0.0f));
            expo[(size_t)b * NC + c]  = -d;
            cdiff[(size_t)b * NC + c] = d;
        }
    }
}

extern "C" void kernel_launch(void* const* d_in, const int* in_sizes, int n_in,
                              void* d_out, int out_size, void* d_ws, size_t ws_size,
                              hipStream_t stream) {
    const float* x        = (const float*)d_in[0];
    const float* means    = (const float*)d_in[1];
    const float* variance = (const float*)d_in[2];
    float* out = (float*)d_out;

    dim3 g(NB / 32, NCP / 64);   // (32, 8) = 256 blocks, 8 waves, 1 block/CU

    if (ws_size >= 32 * sizeof(uint)) {
        uint* cnt = (uint*)d_ws;
        hipMemsetAsync(cnt, 0, 32 * sizeof(uint), stream);
        ncm_dist_fused<<<g, 512, 0, stream>>>(x, means, variance, out, cnt);
        return;
    }

    // fallback: 2-kernel path (R8)
    ncm_dist_only<<<g, 512, 0, stream>>>(x, means, variance, out);
    ncm_softmax_kernel<<<NB, 64, 0, stream>>>(out);
}

// Round 10
// 17.716 us; speedup vs baseline: 2.0346x; 2.0346x over previous
//
#include <hip/hip_runtime.h>
#include <hip/hip_bf16.h>
#include <math.h>

// NCM classifier: B=1024, C=500, F=512 (fp32 in/out).
//   xs = x / variance[0]
//   dist[b][c] = sqrt(sum_f (xs[b][f] - means[c][f])^2)
//   out = concat(softmax(-dist, axis=1), -dist, dist)   // each [B][C]
//
// dist^2 = ||xs||^2 + ||m||^2 - 2*(xs.m), cross term via bf16 MFMA (K=512).
// PROVEN BEST (R8, 17.76 us): 2 kernels, no workspace.
//   k1: fused dist — per-block LDS staging (fp32->bf16 convert + exact fp32
//       norms), then 16x16 MFMA tiles from LDS, epilogue writes -dist/dist.
//       Block = 32 b-rows x 64 classes, 8 waves, grid (32,8) -> 1 block/CU.
//   k2: softmax, one wave per row.
// R9 lesson: a captured hipMemsetAsync node costs ~18+ us of replay time
// (fillBufferAligned fixed dispatch latency) — never add memset nodes.
#define NB 1024
#define NC 500
#define NCP 512
#define NF 512
#define LSTR 520   // LDS row stride (bf16): 1040 B, 16B-aligned, bank-spread

typedef __attribute__((ext_vector_type(8))) short bf16x8;
typedef __attribute__((ext_vector_type(4))) float f32x4;

union bfpack { bf16x8 v; __hip_bfloat162 h[4]; };

// ---- k1: fused stage + GEMM + distance epilogue ----------------------------
__global__ __launch_bounds__(512) void ncm_dist_fused(
    const float* __restrict__ x, const float* __restrict__ means,
    const float* __restrict__ variance, float* __restrict__ out)
{
    __shared__ ushort sA[32][LSTR];   // x rows (bf16, scaled)   65.0 KB
    __shared__ ushort sB[64][LSTR];   // means rows (bf16)       (A+B = 99.8 KB)
    __shared__ float  sNx[32];        // ||xs||^2 (exact fp32)
    __shared__ float  sNm[64];        // ||m||^2  (exact fp32)

    const int t    = threadIdx.x;
    const int w    = t >> 6;          // wave 0..7
    const int lane = t & 63;
    const int fr   = lane & 15;
    const int g    = lane >> 4;
    const int b0   = blockIdx.x * 32;
    const int c0   = blockIdx.y * 64;
    const float inv_var = 1.0f / variance[0];

    // ---- stage: 96 rows (32 x + 64 means), 12 rows per wave ----
    #pragma unroll
    for (int j = 0; j < 12; ++j) {
        const int ri = w * 12 + j;            // 0..95
        const float* src;
        ushort* dst;
        float* nrm;
        float scale;
        bool zero = false;
        if (ri < 32) {
            src = x + (size_t)(b0 + ri) * NF;  dst = &sA[ri][0];
            nrm = &sNx[ri];                    scale = inv_var;
        } else {
            const int cm = c0 + ri - 32;
            src = means + (size_t)cm * NF;     dst = &sB[ri - 32][0];
            nrm = &sNm[ri - 32];               scale = 1.0f;
            zero = (cm >= NC);
        }

        float4 v0, v1;
        if (!zero) {
            v0 = *reinterpret_cast<const float4*>(&src[lane * 8]);
            v1 = *reinterpret_cast<const float4*>(&src[lane * 8 + 4]);
            v0.x *= scale; v0.y *= scale; v0.z *= scale; v0.w *= scale;
            v1.x *= scale; v1.y *= scale; v1.z *= scale; v1.w *= scale;
        } else {
            v0 = make_float4(0.f, 0.f, 0.f, 0.f);
            v1 = v0;
        }
        bfpack p;
        p.h[0] = __float22bfloat162_rn(make_float2(v0.x, v0.y));
        p.h[1] = __float22bfloat162_rn(make_float2(v0.z, v0.w));
        p.h[2] = __float22bfloat162_rn(make_float2(v1.x, v1.y));
        p.h[3] = __float22bfloat162_rn(make_float2(v1.z, v1.w));
        *reinterpret_cast<bf16x8*>(&dst[lane * 8]) = p.v;

        float s = v0.x * v0.x + v0.y * v0.y + v0.z * v0.z + v0.w * v0.w
                + v1.x * v1.x + v1.y * v1.y + v1.z * v1.z + v1.w * v1.w;
        #pragma unroll
        for (int off = 32; off > 0; off >>= 1) s += __shfl_xor(s, off, 64);
        if (lane == 0) *nrm = s;
    }
    __syncthreads();

    // ---- MFMA: wave w -> 16x16 tile at (b-half w>>2, c-quarter w&3) ----
    const int ar = (w >> 2) * 16 + fr;    // local A row
    const int br = (w & 3) * 16 + fr;     // local B row
    const ushort* ap = &sA[ar][g * 8];
    const ushort* bp = &sB[br][g * 8];

    f32x4 acc = {0.f, 0.f, 0.f, 0.f};
    #pragma unroll
    for (int ks = 0; ks < 16; ++ks) {
        bf16x8 a = *reinterpret_cast<const bf16x8*>(ap + ks * 32);
        bf16x8 b = *reinterpret_cast<const bf16x8*>(bp + ks * 32);
        acc = __builtin_amdgcn_mfma_f32_16x16x32_bf16(a, b, acc, 0, 0, 0);
    }

    // C/D layout (m89/m91): col = lane&15 -> class, row = g*4+r -> b-row
    const int c = c0 + (w & 3) * 16 + fr;
    if (c < NC) {
        const float nmc = sNm[(w & 3) * 16 + fr];
        float* expo  = out + (size_t)NB * NC;
        float* cdiff = out + (size_t)2 * NB * NC;
        #pragma unroll
        for (int r = 0; r < 4; ++r) {
            const int bl = (w >> 2) * 16 + g * 4 + r;   // local b row
            const int b  = b0 + bl;
            float d2 = sNx[bl] + nmc - 2.0f * acc[r];
            float d = sqrtf(fmaxf(d2, 0.0f));
            expo[(size_t)b * NC + c]  = -d;
            cdiff[(size_t)b * NC + c] = d;
        }
    }
}

// ---- k2: softmax over C=500, one wave per row ------------------------------
__global__ __launch_bounds__(64) void ncm_softmax_kernel(float* __restrict__ out)
{
    const int b = blockIdx.x;
    const int lane = threadIdx.x;
    const float* expo = out + (size_t)NB * NC + (size_t)b * NC;
    float* probs = out + (size_t)b * NC;

    const int base = lane * 8;
    const bool val0 = base + 3 < NC;   // lanes 0..62
    const bool val1 = base + 7 < NC;   // lanes 0..61
    const float4 ninf = make_float4(-1e30f, -1e30f, -1e30f, -1e30f);

    float4 v0 = val0 ? *reinterpret_cast<const float4*>(&expo[base])     : ninf;
    float4 v1 = val1 ? *reinterpret_cast<const float4*>(&expo[base + 4]) : ninf;

    float m = fmaxf(fmaxf(fmaxf(v0.x, v0.y), fmaxf(v0.z, v0.w)),
                    fmaxf(fmaxf(v1.x, v1.y), fmaxf(v1.z, v1.w)));
    #pragma unroll
    for (int off = 32; off > 0; off >>= 1)
        m = fmaxf(m, __shfl_xor(m, off, 64));

    float4 e0, e1;
    e0.x = expf(v0.x - m); e0.y = expf(v0.y - m);
    e0.z = expf(v0.z - m); e0.w = expf(v0.w - m);
    e1.x = expf(v1.x - m); e1.y = expf(v1.y - m);
    e1.z = expf(v1.z - m); e1.w = expf(v1.w - m);

    float s = e0.x + e0.y + e0.z + e0.w + e1.x + e1.y + e1.z + e1.w;
    #pragma unroll
    for (int off = 32; off > 0; off >>= 1)
        s += __shfl_xor(s, off, 64);
    float inv = 1.0f / s;

    e0.x *= inv; e0.y *= inv; e0.z *= inv; e0.w *= inv;
    e1.x *= inv; e1.y *= inv; e1.z *= inv; e1.w *= inv;

    if (val0) *reinterpret_cast<float4*>(&probs[base])     = e0;
    if (val1) *reinterpret_cast<float4*>(&probs[base + 4]) = e1;
}

extern "C" void kernel_launch(void* const* d_in, const int* in_sizes, int n_in,
                              void* d_out, int out_size, void* d_ws, size_t ws_size,
                              hipStream_t stream) {
    const float* x        = (const float*)d_in[0];
    const float* means    = (const float*)d_in[1];
    const float* variance = (const float*)d_in[2];
    float* out = (float*)d_out;

    dim3 g(NB / 32, NCP / 64);   // (32, 8) = 256 blocks, 8 waves, 1 block/CU
    ncm_dist_fused<<<g, 512, 0, stream>>>(x, means, variance, out);
    ncm_softmax_kernel<<<NB, 64, 0, stream>>>(out);
}